// Round 2
// baseline (2127.656 us; speedup 1.0000x reference)
//
#include <hip/hip_runtime.h>
#include <hip/hip_bf16.h>

#define RES_ 0.16f
#define XMIN_ -51.2f
#define YMIN_ -51.2f
#define EPS_ 1e-5f
#define NEG_ -1000000000.0f

#define WPB 4  // waves per block

__global__ __launch_bounds__(256, 4) void pfn_kernel(
    const float* __restrict__ pillars,
    const int* __restrict__ coords,
    const int* __restrict__ npts_arr,
    const float* __restrict__ W1, const float* __restrict__ b1,
    const float* __restrict__ g1, const float* __restrict__ beta1,
    const float* __restrict__ m1, const float* __restrict__ v1,
    const float* __restrict__ W2, const float* __restrict__ b2,
    const float* __restrict__ g2, const float* __restrict__ beta2,
    const float* __restrict__ m2, const float* __restrict__ v2,
    float* __restrict__ out, int P)
{
    __shared__ float pts[WPB][32][4];      // 2 KB
    __shared__ float h1buf[WPB][32][64];   // 32 KB

    const int tid  = threadIdx.x;
    const int wave = tid >> 6;
    const int lane = tid & 63;
    const int c    = lane;                 // output channel owned by this lane

    // ---- per-channel constants (amortized over ~24 pillars/wave) ----
    float w1r[9];
#pragma unroll
    for (int k = 0; k < 9; ++k) w1r[k] = W1[k * 64 + c];
    const float w1x = w1r[4] + w1r[7];     // xo appears at k=4 and k=7
    const float w1y = w1r[5] + w1r[8];     // yo appears at k=5 and k=8
    const float a1  = g1[c] * rsqrtf(v1[c] + EPS_);
    const float c1f = fmaf(a1, b1[c] - m1[c], beta1[c]);   // fold b1 - BN shift

    float w2c[64];
#pragma unroll
    for (int j = 0; j < 64; ++j) w2c[j] = W2[j * 64 + c];
    const float a2  = g2[c] * rsqrtf(v2[c] + EPS_);
    const float c2f = fmaf(a2, b2[c] - m2[c], beta2[c]);

    const int wave_id = blockIdx.x * WPB + wave;
    const int nwaves  = gridDim.x * WPB;

    for (int p = wave_id; p < P; p += nwaves) {
        int npts = npts_arr[p];
        npts = npts < 0 ? 0 : (npts > 32 ? 32 : npts);
        const float xc = ((float)coords[2 * p + 1] + 0.5f) * RES_ + XMIN_;
        const float yc = ((float)coords[2 * p + 0] + 0.5f) * RES_ + YMIN_;

        // ---- stage pillar points: 128 floats, one float2 per lane ----
        const float2 pv = ((const float2*)(pillars + (size_t)p * 128))[lane];
        ((float2*)&pts[wave][0][0])[lane] = pv;
        __threadfence_block();   // wave-lockstep; lgkmcnt drain makes cross-lane LDS visible

        // ---- z_mean over valid points (butterfly within each 32-half) ----
        const int mz = lane & 31;
        float zv = (mz < npts) ? pts[wave][mz][2] : 0.0f;
#pragma unroll
        for (int off = 1; off <= 16; off <<= 1) zv += __shfl_xor(zv, off, 64);
        const float z_mean = zv / fmaxf((float)npts, 1.0f);

        // ---- layer 1: h1[m][c] for valid m only ----
        for (int m = 0; m < npts; ++m) {
            const float4 pt = *(const float4*)&pts[wave][m][0];  // broadcast read
            const float xo = pt.x - xc;
            const float yo = pt.y - yc;
            const float zo = pt.z - z_mean;
            float d = pt.x * w1r[0];
            d = fmaf(pt.y, w1r[1], d);
            d = fmaf(pt.z, w1r[2], d);
            d = fmaf(pt.w, w1r[3], d);
            d = fmaf(xo, w1x, d);
            d = fmaf(yo, w1y, d);
            d = fmaf(zo, w1r[6], d);
            h1buf[wave][m][c] = fmaxf(fmaf(a1, d, c1f), 0.0f);
        }
        __threadfence_block();

        // ---- layer 2 + masked max (skip invalid m entirely; ReLU>=0 > NEG) ----
        float hm = NEG_;
        for (int m = 0; m < npts; ++m) {
            float acc = 0.0f;
#pragma unroll
            for (int j = 0; j < 64; j += 4) {
                const float4 hv = *(const float4*)&h1buf[wave][m][j];  // broadcast
                acc = fmaf(hv.x, w2c[j + 0], acc);
                acc = fmaf(hv.y, w2c[j + 1], acc);
                acc = fmaf(hv.z, w2c[j + 2], acc);
                acc = fmaf(hv.w, w2c[j + 3], acc);
            }
            const float h2 = fmaxf(fmaf(a2, acc, c2f), 0.0f);
            hm = fmaxf(hm, h2);
        }

        out[(size_t)p * 64 + c] = hm;   // f32 output — reference output dtype is float32
        // next pillar's LDS writes are WAR-safe: DS ops complete in order per wave
    }
}

extern "C" void kernel_launch(void* const* d_in, const int* in_sizes, int n_in,
                              void* d_out, int out_size, void* d_ws, size_t ws_size,
                              hipStream_t stream) {
    const float* pillars = (const float*)d_in[0];
    const int*   coords  = (const int*)d_in[1];
    const int*   npts    = (const int*)d_in[2];
    const float* W1      = (const float*)d_in[3];
    const float* b1      = (const float*)d_in[4];
    const float* g1      = (const float*)d_in[5];
    const float* beta1   = (const float*)d_in[6];
    const float* m1      = (const float*)d_in[7];
    const float* v1      = (const float*)d_in[8];
    const float* W2      = (const float*)d_in[9];
    const float* b2      = (const float*)d_in[10];
    const float* g2      = (const float*)d_in[11];
    const float* beta2   = (const float*)d_in[12];
    const float* m2      = (const float*)d_in[13];
    const float* v2      = (const float*)d_in[14];
    float* out           = (float*)d_out;

    const int P = in_sizes[2];          // num_points_per_pillar element count
    const int blocks = 1024;            // 4 waves/block, grid-stride over pillars

    hipLaunchKernelGGL(pfn_kernel, dim3(blocks), dim3(256), 0, stream,
                       pillars, coords, npts, W1, b1, g1, beta1, m1, v1,
                       W2, b2, g2, beta2, m2, v2, out, P);
}

// Round 3
// 210.845 us; speedup vs baseline: 10.0911x; 10.0911x over previous
//
#include <hip/hip_runtime.h>
#include <hip/hip_bf16.h>

#define RES_ 0.16f
#define XMIN_ -51.2f
#define YMIN_ -51.2f
#define EPS_ 1e-5f
#define NEG_ -1000000000.0f

#define WPB 4  // waves per block

typedef _Float16 f16x8 __attribute__((ext_vector_type(8)));
typedef float f32x4 __attribute__((ext_vector_type(4)));

__global__ __launch_bounds__(256, 2) void pfn_kernel(
    const float* __restrict__ pillars,
    const int* __restrict__ coords,
    const int* __restrict__ npts_arr,
    const float* __restrict__ W1, const float* __restrict__ b1,
    const float* __restrict__ g1, const float* __restrict__ beta1,
    const float* __restrict__ m1, const float* __restrict__ v1,
    const float* __restrict__ W2, const float* __restrict__ b2,
    const float* __restrict__ g2, const float* __restrict__ beta2,
    const float* __restrict__ m2, const float* __restrict__ v2,
    float* __restrict__ out, int P)
{
    __shared__ float pts[WPB][32][4];                        // 2 KB
    __shared__ __align__(16) _Float16 h1s[WPB][32][72];      // 18 KB (pad 64->72 kills A-read bank conflicts)

    const int tid  = threadIdx.x;
    const int wave = tid >> 6;
    const int lane = tid & 63;
    const int c    = lane;          // layer-1 channel owned by this lane
    const int quad = lane >> 4;     // MFMA quad
    const int col  = lane & 15;     // MFMA col-within-tile / row-within-tile

    // ---- layer-1 per-channel constants (lane = channel c) ----
    float w1r[9];
#pragma unroll
    for (int k = 0; k < 9; ++k) w1r[k] = W1[k * 64 + c];
    const float w1x = w1r[4] + w1r[7];     // xo at k=4 and k=7
    const float w1y = w1r[5] + w1r[8];     // yo at k=5 and k=8
    const float a1  = g1[c] * rsqrtf(v1[c] + EPS_);
    const float c1f = fmaf(a1, b1[c] - m1[c], beta1[c]);

    // ---- W2 as MFMA B-fragments, resident in VGPRs (32 regs) ----
    // B-operand layout for 16x16x32: lane holds B[k = quad*8+j][n = nt*16+col]
    f16x8 bw[2][4];
#pragma unroll
    for (int kt = 0; kt < 2; ++kt)
#pragma unroll
        for (int nt = 0; nt < 4; ++nt)
#pragma unroll
            for (int j = 0; j < 8; ++j)
                bw[kt][nt][j] = (_Float16)W2[(kt * 32 + quad * 8 + j) * 64 + nt * 16 + col];

    // ---- layer-2 BN constants per output column n = nt*16+col ----
    float a2f[4], c2b[4];
#pragma unroll
    for (int nt = 0; nt < 4; ++nt) {
        const int n = nt * 16 + col;
        a2f[nt] = g2[n] * rsqrtf(v2[n] + EPS_);
        c2b[nt] = fmaf(a2f[nt], b2[n] - m2[n], beta2[n]);
    }

    const int wave_id = blockIdx.x * WPB + wave;
    const int nwaves  = gridDim.x * WPB;

    for (int p = wave_id; p < P; p += nwaves) {
        int npts = npts_arr[p];
        npts = npts < 0 ? 0 : (npts > 32 ? 32 : npts);
        const float xc = ((float)coords[2 * p + 1] + 0.5f) * RES_ + XMIN_;
        const float yc = ((float)coords[2 * p + 0] + 0.5f) * RES_ + YMIN_;

        // ---- stage 32x4 points: one float2 per lane ----
        const float2 pv = ((const float2*)(pillars + (size_t)p * 128))[lane];
        ((float2*)&pts[wave][0][0])[lane] = pv;
        __threadfence_block();   // wave-lockstep + lgkm drain

        // ---- z_mean over valid points ----
        const int mz = lane & 31;
        float zv = (mz < npts) ? pts[wave][mz][2] : 0.0f;
#pragma unroll
        for (int off = 1; off <= 16; off <<= 1) zv += __shfl_xor(zv, off, 64);
        const float z_mean = zv / fmaxf((float)npts, 1.0f);

        // ---- layer 1 (VALU): all 32 rows; lane c computes h1[m][c] ----
#pragma unroll 4
        for (int m = 0; m < 32; ++m) {
            const float4 pt = *(const float4*)&pts[wave][m][0];  // broadcast
            const float xo = pt.x - xc;
            const float yo = pt.y - yc;
            const float zo = pt.z - z_mean;
            float d = pt.x * w1r[0];
            d = fmaf(pt.y, w1r[1], d);
            d = fmaf(pt.z, w1r[2], d);
            d = fmaf(pt.w, w1r[3], d);
            d = fmaf(xo, w1x, d);
            d = fmaf(yo, w1y, d);
            d = fmaf(zo, w1r[6], d);
            h1s[wave][m][c] = (_Float16)fmaxf(fmaf(a1, d, c1f), 0.0f);
        }
        __threadfence_block();

        // ---- A-fragments: A[m = mt*16+col][k = kt*32 + quad*8 + j] ----
        f16x8 av[2][2];
#pragma unroll
        for (int mt = 0; mt < 2; ++mt)
#pragma unroll
            for (int kt = 0; kt < 2; ++kt)
                av[mt][kt] = *(const f16x8*)&h1s[wave][mt * 16 + col][kt * 32 + quad * 8];

        // ---- 16x MFMA: h1(32x64) @ W2(64x64) ----
        f32x4 acc[2][4];
#pragma unroll
        for (int mt = 0; mt < 2; ++mt)
#pragma unroll
            for (int nt = 0; nt < 4; ++nt) {
                f32x4 a = {0.f, 0.f, 0.f, 0.f};
                a = __builtin_amdgcn_mfma_f32_16x16x32_f16(av[mt][0], bw[0][nt], a, 0, 0, 0);
                a = __builtin_amdgcn_mfma_f32_16x16x32_f16(av[mt][1], bw[1][nt], a, 0, 0, 0);
                acc[mt][nt] = a;
            }

        // ---- epilogue: BN2+ReLU, mask m<npts, max over rows ----
        // C/D layout: col = lane&15 (within nt tile), row = quad*4 + reg (within mt tile)
        float hmv[4];
#pragma unroll
        for (int nt = 0; nt < 4; ++nt) {
            float hm = NEG_;
#pragma unroll
            for (int mt = 0; mt < 2; ++mt)
#pragma unroll
                for (int r = 0; r < 4; ++r) {
                    const int m = mt * 16 + quad * 4 + r;
                    const float val = fmaxf(fmaf(a2f[nt], acc[mt][nt][r], c2b[nt]), 0.0f);
                    hm = (m < npts) ? fmaxf(hm, val) : hm;
                }
            // reduce over the 4 quads (rows live in different quads)
            hm = fmaxf(hm, __shfl_xor(hm, 16, 64));
            hm = fmaxf(hm, __shfl_xor(hm, 32, 64));
            hmv[nt] = hm;
        }
        // lane l owns output column l = quad*16 + col -> pick nt == quad
        const float r0 = (quad == 0) ? hmv[0] : (quad == 1) ? hmv[1] : (quad == 2) ? hmv[2] : hmv[3];
        out[(size_t)p * 64 + lane] = r0;
    }
}

extern "C" void kernel_launch(void* const* d_in, const int* in_sizes, int n_in,
                              void* d_out, int out_size, void* d_ws, size_t ws_size,
                              hipStream_t stream) {
    const float* pillars = (const float*)d_in[0];
    const int*   coords  = (const int*)d_in[1];
    const int*   npts    = (const int*)d_in[2];
    const float* W1      = (const float*)d_in[3];
    const float* b1      = (const float*)d_in[4];
    const float* g1      = (const float*)d_in[5];
    const float* beta1   = (const float*)d_in[6];
    const float* m1      = (const float*)d_in[7];
    const float* v1      = (const float*)d_in[8];
    const float* W2      = (const float*)d_in[9];
    const float* b2      = (const float*)d_in[10];
    const float* g2      = (const float*)d_in[11];
    const float* beta2   = (const float*)d_in[12];
    const float* m2      = (const float*)d_in[13];
    const float* v2      = (const float*)d_in[14];
    float* out           = (float*)d_out;

    const int P = in_sizes[2];
    const int blocks = 1024;   // 4096 waves, ~24 pillars each

    hipLaunchKernelGGL(pfn_kernel, dim3(blocks), dim3(256), 0, stream,
                       pillars, coords, npts, W1, b1, g1, beta1, m1, v1,
                       W2, b2, g2, beta2, m2, v2, out, P);
}

// Round 4
// 185.005 us; speedup vs baseline: 11.5005x; 1.1397x over previous
//
#include <hip/hip_runtime.h>

#define RES_ 0.16f
#define XMIN_ -51.2f
#define YMIN_ -51.2f
#define EPS_ 1e-5f
#define NEG_ -1000000000.0f

#define WPB 4  // waves per block

typedef _Float16 f16x8 __attribute__((ext_vector_type(8)));
typedef float f32x4 __attribute__((ext_vector_type(4)));

__global__ __launch_bounds__(256, 2) void pfn_kernel(
    const float* __restrict__ pillars,
    const int* __restrict__ coords,
    const int* __restrict__ npts_arr,
    const float* __restrict__ W1, const float* __restrict__ b1,
    const float* __restrict__ g1, const float* __restrict__ beta1,
    const float* __restrict__ m1, const float* __restrict__ v1,
    const float* __restrict__ W2, const float* __restrict__ b2,
    const float* __restrict__ g2, const float* __restrict__ beta2,
    const float* __restrict__ m2, const float* __restrict__ v2,
    float* __restrict__ out, int P)
{
    __shared__ float pts[WPB][32][4];                        // 2 KB
    __shared__ __align__(16) _Float16 h1s[WPB][32][72];      // 18 KB (pad 64->72: A-reads 2-way only)

    const int tid  = threadIdx.x;
    const int wave = tid >> 6;
    const int lane = tid & 63;
    const int quad = lane >> 4;     // MFMA quad
    const int col  = lane & 15;

    // ---- W1 as MFMA B-fragments (K padded 9->32), resident: 16 VGPRs ----
    // B layout (16x16x32): lane holds B[k = quad*8+j][n = nt*16+col]
    f16x8 bw1[4];
#pragma unroll
    for (int nt = 0; nt < 4; ++nt)
#pragma unroll
        for (int j = 0; j < 8; ++j) {
            const int k = quad * 8 + j;
            bw1[nt][j] = (k < 9) ? (_Float16)W1[k * 64 + nt * 16 + col] : (_Float16)0.f;
        }
    // BN1 constants per channel n = nt*16+col
    float a1v[4], c1v[4];
#pragma unroll
    for (int nt = 0; nt < 4; ++nt) {
        const int n = nt * 16 + col;
        a1v[nt] = g1[n] * rsqrtf(v1[n] + EPS_);
        c1v[nt] = fmaf(a1v[nt], b1[n] - m1[n], beta1[n]);
    }

    // ---- W2 as MFMA B-fragments: 32 VGPRs ----
    f16x8 bw2[2][4];
#pragma unroll
    for (int kt = 0; kt < 2; ++kt)
#pragma unroll
        for (int nt = 0; nt < 4; ++nt)
#pragma unroll
            for (int j = 0; j < 8; ++j)
                bw2[kt][nt][j] = (_Float16)W2[(kt * 32 + quad * 8 + j) * 64 + nt * 16 + col];
    // BN2 constants
    float a2f[4], c2b[4];
#pragma unroll
    for (int nt = 0; nt < 4; ++nt) {
        const int n = nt * 16 + col;
        a2f[nt] = g2[n] * rsqrtf(v2[n] + EPS_);
        c2b[nt] = fmaf(a2f[nt], b2[n] - m2[n], beta2[n]);
    }

    const int wave_id = blockIdx.x * WPB + wave;
    const int nwaves  = gridDim.x * WPB;

    for (int p = wave_id; p < P; p += nwaves) {
        int npts = npts_arr[p];
        npts = npts < 0 ? 0 : (npts > 32 ? 32 : npts);
        const float xc = ((float)coords[2 * p + 1] + 0.5f) * RES_ + XMIN_;
        const float yc = ((float)coords[2 * p + 0] + 0.5f) * RES_ + YMIN_;

        // ---- stage 32x4 points ----
        const float2 pv = ((const float2*)(pillars + (size_t)p * 128))[lane];
        ((float2*)&pts[wave][0][0])[lane] = pv;
        __threadfence_block();   // wave-lockstep + lgkm drain

        // ---- z_mean over valid points ----
        const int mz = lane & 31;
        float zv = (mz < npts) ? pts[wave][mz][2] : 0.0f;
#pragma unroll
        for (int off = 1; off <= 16; off <<= 1) zv += __shfl_xor(zv, off, 64);
        const float z_mean = zv / fmaxf((float)npts, 1.0f);

        // ---- layer-1 A-fragments built in registers ----
        // A[m = mt*16+col][k = quad*8+j]; feat = {x,y,z,r,xo,yo,zo,xo,yo,0..}
        f16x8 av1[2];
#pragma unroll
        for (int mt = 0; mt < 2; ++mt) {
            const float4 pt = *(const float4*)&pts[wave][mt * 16 + col][0];
            const _Float16 hx = (_Float16)pt.x;
            const _Float16 hy = (_Float16)pt.y;
            const _Float16 hz = (_Float16)pt.z;
            const _Float16 hr = (_Float16)pt.w;
            const _Float16 ho = (_Float16)(pt.x - xc);
            const _Float16 hp = (_Float16)(pt.y - yc);
            const _Float16 hq = (_Float16)(pt.z - z_mean);
            const _Float16 z0 = (_Float16)0.f;
            f16x8 v;
            v[0] = (quad == 0) ? hx : (quad == 1) ? hp : z0;  // k=0:x | k=8:yo
            v[1] = (quad == 0) ? hy : z0;
            v[2] = (quad == 0) ? hz : z0;
            v[3] = (quad == 0) ? hr : z0;
            v[4] = (quad == 0) ? ho : z0;
            v[5] = (quad == 0) ? hp : z0;
            v[6] = (quad == 0) ? hq : z0;
            v[7] = (quad == 0) ? ho : z0;
            av1[mt] = v;
        }

        // ---- layer-1 MFMA: feat(32x32pad) @ W1(32pad x 64) ----
        f32x4 acc1[2][4];
#pragma unroll
        for (int mt = 0; mt < 2; ++mt)
#pragma unroll
            for (int nt = 0; nt < 4; ++nt) {
                f32x4 z = {0.f, 0.f, 0.f, 0.f};
                acc1[mt][nt] = __builtin_amdgcn_mfma_f32_16x16x32_f16(av1[mt], bw1[nt], z, 0, 0, 0);
            }

        // ---- BN1 + ReLU, write h1 to LDS (C/D: row = quad*4+r, col-channel) ----
#pragma unroll
        for (int mt = 0; mt < 2; ++mt)
#pragma unroll
            for (int nt = 0; nt < 4; ++nt)
#pragma unroll
                for (int r = 0; r < 4; ++r) {
                    const int m = mt * 16 + quad * 4 + r;
                    const float h = fmaxf(fmaf(a1v[nt], acc1[mt][nt][r], c1v[nt]), 0.0f);
                    h1s[wave][m][nt * 16 + col] = (_Float16)h;
                }
        __threadfence_block();

        // ---- layer-2 A-fragments from LDS ----
        f16x8 av2[2][2];
#pragma unroll
        for (int mt = 0; mt < 2; ++mt)
#pragma unroll
            for (int kt = 0; kt < 2; ++kt)
                av2[mt][kt] = *(const f16x8*)&h1s[wave][mt * 16 + col][kt * 32 + quad * 8];

        // ---- layer-2 MFMA: h1(32x64) @ W2(64x64) ----
        f32x4 acc[2][4];
#pragma unroll
        for (int mt = 0; mt < 2; ++mt)
#pragma unroll
            for (int nt = 0; nt < 4; ++nt) {
                f32x4 a = {0.f, 0.f, 0.f, 0.f};
                a = __builtin_amdgcn_mfma_f32_16x16x32_f16(av2[mt][0], bw2[0][nt], a, 0, 0, 0);
                a = __builtin_amdgcn_mfma_f32_16x16x32_f16(av2[mt][1], bw2[1][nt], a, 0, 0, 0);
                acc[mt][nt] = a;
            }

        // ---- BN2 + ReLU, mask, max over rows ----
        float hmv[4];
#pragma unroll
        for (int nt = 0; nt < 4; ++nt) {
            float hm = NEG_;
#pragma unroll
            for (int mt = 0; mt < 2; ++mt)
#pragma unroll
                for (int r = 0; r < 4; ++r) {
                    const int m = mt * 16 + quad * 4 + r;
                    const float val = fmaxf(fmaf(a2f[nt], acc[mt][nt][r], c2b[nt]), 0.0f);
                    hm = (m < npts) ? fmaxf(hm, val) : hm;
                }
            hm = fmaxf(hm, __shfl_xor(hm, 16, 64));
            hm = fmaxf(hm, __shfl_xor(hm, 32, 64));
            hmv[nt] = hm;
        }
        const float r0 = (quad == 0) ? hmv[0] : (quad == 1) ? hmv[1] : (quad == 2) ? hmv[2] : hmv[3];
        out[(size_t)p * 64 + lane] = r0;
    }
}

extern "C" void kernel_launch(void* const* d_in, const int* in_sizes, int n_in,
                              void* d_out, int out_size, void* d_ws, size_t ws_size,
                              hipStream_t stream) {
    const float* pillars = (const float*)d_in[0];
    const int*   coords  = (const int*)d_in[1];
    const int*   npts    = (const int*)d_in[2];
    const float* W1      = (const float*)d_in[3];
    const float* b1      = (const float*)d_in[4];
    const float* g1      = (const float*)d_in[5];
    const float* beta1   = (const float*)d_in[6];
    const float* m1      = (const float*)d_in[7];
    const float* v1      = (const float*)d_in[8];
    const float* W2      = (const float*)d_in[9];
    const float* b2      = (const float*)d_in[10];
    const float* g2      = (const float*)d_in[11];
    const float* beta2   = (const float*)d_in[12];
    const float* m2      = (const float*)d_in[13];
    const float* v2      = (const float*)d_in[14];
    float* out           = (float*)d_out;

    const int P = in_sizes[2];
    const int blocks = 2048;   // 8192 waves, ~12 pillars each; occupancy no longer grid-limited

    hipLaunchKernelGGL(pfn_kernel, dim3(blocks), dim3(256), 0, stream,
                       pillars, coords, npts, W1, b1, g1, beta1, m1, v1,
                       W2, b2, g2, beta2, m2, v2, out, P);
}